// Round 3
// baseline (440.731 us; speedup 1.0000x reference)
//
#include <hip/hip_runtime.h>

// 3-layer SplineConv (3x3 kernel, degree 2, open spline), fused per layer.
// Edges are counting-sorted by src once (CSR). Each block owns TN=32 nodes:
//   phase 1: y_tile[32][288] = X_tile @ [W0..W8] into LDS; root+bias term
//            atomicAdd'ed into pre-zeroed agg (owner-order vs other blocks'
//            edge atomics is undefined, so everything goes through atomics).
//   phase 2: for the tile's contiguous edge segment, msg[c] = sum q1a q0b
//            sY[src-base][(3a+b)*32+c], atomicAdd into agg[dst].
// y never touches global memory (saves ~115 MB/layer of HBM/L2 round-trip).

#define TN 32

template<int CIN, int MODE>
__global__ __launch_bounds__(256)
void fused_layer(const float* __restrict__ Xa, const float* __restrict__ Xb,
                 const float* __restrict__ W, const float* __restrict__ root,
                 const float* __restrict__ bias,
                 const int* __restrict__ rowend,  // rowend[n] = end of node n's edge segment
                 const int* __restrict__ s_src, const int* __restrict__ s_dst,
                 const float* __restrict__ s_pp,
                 float* __restrict__ agg, int N)
{
    // MODE 0: X = Xa [N,CIN]
    // MODE 1: X[n,i] = i<32 ? relu(Xa[n,i]) : Xb[n,i-32]  (CIN=64)
    // MODE 2: X = relu(Xa) [N,CIN]
    __shared__ float sX[TN][CIN + 1];
    __shared__ float sY[TN][288];   // 288 % 32 == 0: phase-2 reads are 2 lanes/bank (free)

    const int t = threadIdx.x;
    const int base = blockIdx.x * TN;

    // ---- stage X tile (coalesced) ----
    const int TOT = TN * CIN;
    for (int idx = t; idx < TOT; idx += 256) {
        int nl = idx / CIN;
        int i  = idx % CIN;
        int n  = base + nl;
        float v = 0.f;
        if (n < N) {
            if (MODE == 0)      v = Xa[(size_t)n * CIN + i];
            else if (MODE == 1) v = (i < 32) ? fmaxf(Xa[(size_t)n * 32 + i], 0.f)
                                             : Xb[(size_t)n * 32 + (i - 32)];
            else                v = fmaxf(Xa[(size_t)n * CIN + i], 0.f);
        }
        sX[nl][i] = v;
    }
    __syncthreads();

    const int c = t & 31;   // output channel
    const int q = t >> 5;   // 0..7; owns nodes q*4 .. q*4+3

    // ---- phase 1: 40 accumulators/thread (fits VGPRs, no spill) ----
    float acc[4][10];
    #pragma unroll
    for (int j = 0; j < 4; ++j)
        #pragma unroll
        for (int k = 0; k < 10; ++k) acc[j][k] = 0.f;

    for (int i = 0; i < CIN; ++i) {
        float wv[10];
        #pragma unroll
        for (int k = 0; k < 9; ++k)
            wv[k] = W[((size_t)k * CIN + i) * 32 + c];
        wv[9] = root[(size_t)i * 32 + c];
        #pragma unroll
        for (int j = 0; j < 4; ++j) {
            float xv = sX[q * 4 + j][i];
            #pragma unroll
            for (int k = 0; k < 10; ++k)
                acc[j][k] = fmaf(xv, wv[k], acc[j][k]);
        }
    }

    const float bv = bias[c];
    #pragma unroll
    for (int j = 0; j < 4; ++j) {
        int nl = q * 4 + j;
        int n  = base + nl;
        #pragma unroll
        for (int k = 0; k < 9; ++k)
            sY[nl][k * 32 + c] = acc[j][k];
        if (n < N)
            atomicAdd(agg + (size_t)n * 32 + c, acc[j][9] + bv);
    }
    __syncthreads();

    // ---- phase 2: this tile's edge segment (contiguous, src-sorted) ----
    const int lastn = min(base + TN, N) - 1;
    const int e0 = (base == 0) ? 0 : rowend[base - 1];
    const int e1 = rowend[lastn];

    for (int e = e0 + q; e < e1; e += 8) {
        const int src = s_src[e];
        const int dst = s_dst[e];
        const float p0 = s_pp[2 * (size_t)e];
        const float p1 = s_pp[2 * (size_t)e + 1];

        const float q00 = 0.5f * (1.f - p0) * (1.f - p0);
        const float q01 = -p0 * p0 + p0 + 0.5f;
        const float q02 = 0.5f * p0 * p0;
        const float q10 = 0.5f * (1.f - p1) * (1.f - p1);
        const float q11 = -p1 * p1 + p1 + 0.5f;
        const float q12 = 0.5f * p1 * p1;

        const float* yb = &sY[src - base][c];
        float m0 = q00 * yb[0]   + q01 * yb[32]  + q02 * yb[64];
        float m1 = q00 * yb[96]  + q01 * yb[128] + q02 * yb[160];
        float m2 = q00 * yb[192] + q01 * yb[224] + q02 * yb[256];
        float msg = q10 * m0 + q11 * m1 + q12 * m2;

        atomicAdd(agg + (size_t)dst * 32 + c, msg);
    }
}

// ---------- prep: counting sort of edges by src ----------

__global__ __launch_bounds__(1024)
void zero_kernel(int* __restrict__ p, int n)
{
    int i = blockIdx.x * 1024 + threadIdx.x;
    if (i < n) p[i] = 0;
}

__global__ __launch_bounds__(256)
void count_kernel(const int* __restrict__ ei, int* __restrict__ hist, int E)
{
    int e = blockIdx.x * 256 + threadIdx.x;
    if (e < E) atomicAdd(&hist[ei[e]], 1);
}

__global__ __launch_bounds__(1024)
void scan1_kernel(int* __restrict__ hist, int* __restrict__ bsum, int n)
{
    __shared__ int s[1024];
    int tid = threadIdx.x;
    int i = blockIdx.x * 1024 + tid;
    int v = (i < n) ? hist[i] : 0;
    s[tid] = v;
    __syncthreads();
    for (int off = 1; off < 1024; off <<= 1) {
        int add = (tid >= off) ? s[tid - off] : 0;
        __syncthreads();
        s[tid] += add;
        __syncthreads();
    }
    if (i < n) hist[i] = s[tid] - v;          // exclusive within block
    if (tid == 1023) bsum[blockIdx.x] = s[1023];
}

__global__ __launch_bounds__(256)
void scan2_kernel(int* __restrict__ bsum, int nb)
{
    __shared__ int s[256];
    int tid = threadIdx.x;
    int v = (tid < nb) ? bsum[tid] : 0;
    s[tid] = v;
    __syncthreads();
    for (int off = 1; off < 256; off <<= 1) {
        int add = (tid >= off) ? s[tid - off] : 0;
        __syncthreads();
        s[tid] += add;
        __syncthreads();
    }
    if (tid < nb) bsum[tid] = s[tid] - v;     // exclusive
}

__global__ __launch_bounds__(1024)
void scan3_kernel(int* __restrict__ hist, const int* __restrict__ bsum, int n)
{
    int i = blockIdx.x * 1024 + threadIdx.x;
    if (i < n) hist[i] += bsum[blockIdx.x];
}

// place each edge at pos = start[src]++; afterwards start[n] == rowend[n]
__global__ __launch_bounds__(256)
void scatter_kernel(const int* __restrict__ ei, const float* __restrict__ pseudo,
                    int* __restrict__ start,
                    int* __restrict__ s_src, int* __restrict__ s_dst,
                    float* __restrict__ s_pp, int E)
{
    int e = blockIdx.x * 256 + threadIdx.x;
    if (e >= E) return;
    int s = ei[e];
    int d = ei[E + e];
    float p0 = pseudo[2 * (size_t)e];
    float p1 = pseudo[2 * (size_t)e + 1];
    int pos = atomicAdd(&start[s], 1);
    s_src[pos] = s;
    s_dst[pos] = d;
    s_pp[2 * (size_t)pos]     = p0;
    s_pp[2 * (size_t)pos + 1] = p1;
}

__global__ __launch_bounds__(1024)
void relu_kernel(float* __restrict__ p, int n)
{
    int i = blockIdx.x * 1024 + threadIdx.x;
    if (i < n) p[i] = fmaxf(p[i], 0.f);
}

extern "C" void kernel_launch(void* const* d_in, const int* in_sizes, int n_in,
                              void* d_out, int out_size, void* d_ws, size_t ws_size,
                              hipStream_t stream) {
    const float* x      = (const float*)d_in[0];
    const int*   ei     = (const int*)  d_in[1];
    const float* pseudo = (const float*)d_in[2];
    const float* skip   = (const float*)d_in[3];
    const float* W1     = (const float*)d_in[4];
    const float* root1  = (const float*)d_in[5];
    const float* b1     = (const float*)d_in[6];
    const float* W2     = (const float*)d_in[7];
    const float* root2  = (const float*)d_in[8];
    const float* b2     = (const float*)d_in[9];

    const int N = in_sizes[0] / 64;
    const int E = in_sizes[1] / 2;
    float* out = (float*)d_out;

    // ws layout (~19.6 MB): agg1[N*32] agg2[N*32] s_src[E] s_dst[E] s_pp[2E] start[N] bsum[256]
    float* ws    = (float*)d_ws;
    float* agg1  = ws;
    float* agg2  = agg1 + (size_t)N * 32;
    int*   s_src = (int*)(agg2 + (size_t)N * 32);
    int*   s_dst = s_src + E;
    float* s_pp  = (float*)(s_dst + E);
    int*   start = (int*)(s_pp + 2 * (size_t)E);
    int*   bsum  = start + N;

    const dim3 blk(256);
    const int fb   = (N + TN - 1) / TN;
    const int e256 = (E + 255) / 256;
    const int n1k  = (N + 1023) / 1024;

    // ---- zero the atomic targets (d_ws/d_out are poisoned 0xAA each call) ----
    zero_kernel<<<(N * 64 + 1023) / 1024, 1024, 0, stream>>>((int*)agg1, N * 64);
    zero_kernel<<<(N * 32 + 1023) / 1024, 1024, 0, stream>>>((int*)out, N * 32);
    zero_kernel<<<n1k, 1024, 0, stream>>>(start, N);

    // ---- counting sort by src (reused by all 3 layers) ----
    count_kernel<<<e256, blk, 0, stream>>>(ei, start, E);
    scan1_kernel<<<n1k, 1024, 0, stream>>>(start, bsum, N);
    scan2_kernel<<<1, 256, 0, stream>>>(bsum, n1k);
    scan3_kernel<<<n1k, 1024, 0, stream>>>(start, bsum, N);
    scatter_kernel<<<e256, blk, 0, stream>>>(ei, pseudo, start, s_src, s_dst, s_pp, E);
    // start[n] is now rowend[n]

    // ---- 3 fused layers ----
    fused_layer<64, 0><<<fb, blk, 0, stream>>>(x,    nullptr, W1, root1, b1,
                                               start, s_src, s_dst, s_pp, agg1, N);
    fused_layer<64, 1><<<fb, blk, 0, stream>>>(agg1, skip,    W1, root1, b1,
                                               start, s_src, s_dst, s_pp, agg2, N);
    fused_layer<32, 2><<<fb, blk, 0, stream>>>(agg2, nullptr, W2, root2, b2,
                                               start, s_src, s_dst, s_pp, out, N);
    relu_kernel<<<(N * 32 + 1023) / 1024, 1024, 0, stream>>>(out, N * 32);
}

// Round 4
// 438.658 us; speedup vs baseline: 1.0047x; 1.0047x over previous
//
#include <hip/hip_runtime.h>
#include <hip/hip_bf16.h>

// 3-layer SplineConv (3x3, degree 2, open spline). Atomic-free pipeline.
// Prep (once): dual counting sort of edges by src and by dst via ONE 2N-wide
//   scan. Produces: s_src/s_pp (edge data in src order), dpos[e] = dst-sorted
//   slot of src-sorted edge e, rowend_d[n] (dst CSR, offset by E).
// Per layer:
//   transform: y[n,k*32+c] = sum_i X[n,i] W[k,i,c] (bf16 store),
//              agg[n,c] = sum_i X[n,i] root[i,c] + bias[c]  (plain store)
//   msg:       per src-sorted edge e: m[c] = sum_{a,b} q1a q0b y[src,(3a+b)*32+c],
//              store bf16 into msg[dpos[e]*32+c]  (scattered 64B row write, NO atomic)
//   gather:    per node n: agg[n,c] += sum of its contiguous msg rows; relu fused.
// Layer chain: L1(x,W1) -> L2(concat(h1,skip),W1) -> L3(h2,W2).

#define TN 32

template<int CIN, int MODE>
__global__ __launch_bounds__(256)
void transform_kernel(const float* __restrict__ Xa, const float* __restrict__ Xb,
                      const float* __restrict__ W, const float* __restrict__ root,
                      const float* __restrict__ bias,
                      __hip_bfloat16* __restrict__ y, float* __restrict__ agg, int N)
{
    // MODE 0: X = Xa [N,CIN]  (inputs already relu'd where needed)
    // MODE 1: X[n,i] = i<32 ? Xa[n,i] : Xb[n,i-32]   (CIN=64)
    __shared__ float sX[TN][CIN + 1];
    const int t = threadIdx.x;
    const int base = blockIdx.x * TN;

    const int TOT = TN * CIN;
    for (int idx = t; idx < TOT; idx += 256) {
        int nl = idx / CIN;
        int i  = idx % CIN;
        int n  = base + nl;
        float v = 0.f;
        if (n < N) {
            if (MODE == 0) v = Xa[(size_t)n * CIN + i];
            else           v = (i < 32) ? Xa[(size_t)n * 32 + i]
                                        : Xb[(size_t)n * 32 + (i - 32)];
        }
        sX[nl][i] = v;
    }
    __syncthreads();

    const int c = t & 31;   // output channel
    const int q = t >> 5;   // 0..7, owns nodes q*4..q*4+3

    float acc[4][10];       // 40 accumulators/thread: fits VGPRs, no spill
    #pragma unroll
    for (int j = 0; j < 4; ++j)
        #pragma unroll
        for (int k = 0; k < 10; ++k) acc[j][k] = 0.f;

    for (int i = 0; i < CIN; ++i) {
        float wv[10];
        #pragma unroll
        for (int k = 0; k < 9; ++k)
            wv[k] = W[((size_t)k * CIN + i) * 32 + c];
        wv[9] = root[(size_t)i * 32 + c];
        #pragma unroll
        for (int j = 0; j < 4; ++j) {
            float xv = sX[q * 4 + j][i];
            #pragma unroll
            for (int k = 0; k < 10; ++k)
                acc[j][k] = fmaf(xv, wv[k], acc[j][k]);
        }
    }

    const float bv = bias[c];
    #pragma unroll
    for (int j = 0; j < 4; ++j) {
        int n = base + q * 4 + j;
        if (n < N) {
            #pragma unroll
            for (int k = 0; k < 9; ++k)
                y[(size_t)n * 288 + k * 32 + c] = __float2bfloat16(acc[j][k]);
            agg[(size_t)n * 32 + c] = acc[j][9] + bv;
        }
    }
}

// msg: src-sorted edge -> message, stored into dst-sorted slot (no atomics)
__global__ __launch_bounds__(256)
void msg_kernel(const int* __restrict__ s_src, const float* __restrict__ s_pp,
                const int* __restrict__ dpos,
                const __hip_bfloat16* __restrict__ y,
                __hip_bfloat16* __restrict__ msg, int E)
{
    const int t = threadIdx.x;
    const int e = blockIdx.x * 8 + (t >> 5);
    if (e >= E) return;
    const int c = t & 31;

    const int src = s_src[e];
    const int dp  = dpos[e];
    const float p0 = s_pp[2 * (size_t)e];
    const float p1 = s_pp[2 * (size_t)e + 1];

    const float q00 = 0.5f * (1.f - p0) * (1.f - p0);
    const float q01 = -p0 * p0 + p0 + 0.5f;
    const float q02 = 0.5f * p0 * p0;
    const float q10 = 0.5f * (1.f - p1) * (1.f - p1);
    const float q11 = -p1 * p1 + p1 + 0.5f;
    const float q12 = 0.5f * p1 * p1;

    const __hip_bfloat16* yb = y + (size_t)src * 288 + c;
    float m0 = q00 * __bfloat162float(yb[0])   + q01 * __bfloat162float(yb[32])  + q02 * __bfloat162float(yb[64]);
    float m1 = q00 * __bfloat162float(yb[96])  + q01 * __bfloat162float(yb[128]) + q02 * __bfloat162float(yb[160]);
    float m2 = q00 * __bfloat162float(yb[192]) + q01 * __bfloat162float(yb[224]) + q02 * __bfloat162float(yb[256]);
    float mv = q10 * m0 + q11 * m1 + q12 * m2;

    msg[(size_t)dp * 32 + c] = __float2bfloat16(mv);
}

// gather: per node, sum its contiguous dst-sorted msg rows; relu fused
__global__ __launch_bounds__(256)
void gather_kernel(const int* __restrict__ rowend_d,  // values offset by E
                   const __hip_bfloat16* __restrict__ msg,
                   float* __restrict__ agg, int N, int E)
{
    const int t = threadIdx.x;
    const int n = blockIdx.x * 8 + (t >> 5);
    if (n >= N) return;
    const int c = t & 31;

    const int e0 = ((n == 0) ? E : rowend_d[n - 1]) - E;
    const int e1 = rowend_d[n] - E;

    float s = agg[(size_t)n * 32 + c];
    for (int e = e0; e < e1; ++e)
        s += __bfloat162float(msg[(size_t)e * 32 + c]);
    agg[(size_t)n * 32 + c] = fmaxf(s, 0.f);
}

// ---------- prep: dual counting sort (src & dst) with one 2N-wide scan ----------

__global__ __launch_bounds__(1024)
void zero_kernel(int* __restrict__ p, int n)
{
    int i = blockIdx.x * 1024 + threadIdx.x;
    if (i < n) p[i] = 0;
}

__global__ __launch_bounds__(256)
void count_both_kernel(const int* __restrict__ ei, int* __restrict__ hist, int N, int E)
{
    int e = blockIdx.x * 256 + threadIdx.x;
    if (e >= E) return;
    atomicAdd(&hist[ei[e]], 1);          // src in [0,N)
    atomicAdd(&hist[N + ei[E + e]], 1);  // dst in [N,2N)
}

__global__ __launch_bounds__(1024)
void scan1_kernel(int* __restrict__ hist, int* __restrict__ bsum, int n)
{
    __shared__ int s[1024];
    int tid = threadIdx.x;
    int i = blockIdx.x * 1024 + tid;
    int v = (i < n) ? hist[i] : 0;
    s[tid] = v;
    __syncthreads();
    for (int off = 1; off < 1024; off <<= 1) {
        int add = (tid >= off) ? s[tid - off] : 0;
        __syncthreads();
        s[tid] += add;
        __syncthreads();
    }
    if (i < n) hist[i] = s[tid] - v;          // exclusive within block
    if (tid == 1023) bsum[blockIdx.x] = s[1023];
}

__global__ __launch_bounds__(256)
void scan2_kernel(int* __restrict__ bsum, int nb)
{
    __shared__ int s[256];
    int tid = threadIdx.x;
    int v = (tid < nb) ? bsum[tid] : 0;
    s[tid] = v;
    __syncthreads();
    for (int off = 1; off < 256; off <<= 1) {
        int add = (tid >= off) ? s[tid - off] : 0;
        __syncthreads();
        s[tid] += add;
        __syncthreads();
    }
    if (tid < nb) bsum[tid] = s[tid] - v;     // exclusive
}

__global__ __launch_bounds__(1024)
void scan3_kernel(int* __restrict__ hist, const int* __restrict__ bsum, int n)
{
    int i = blockIdx.x * 1024 + threadIdx.x;
    if (i < n) hist[i] += bsum[blockIdx.x];
}

// place edge in BOTH orders; record cross-link dpos[src_slot] = dst_slot
__global__ __launch_bounds__(256)
void scatter_both_kernel(const int* __restrict__ ei, const float* __restrict__ pseudo,
                         int* __restrict__ start,   // [0,N)=src cursors, [N,2N)=dst cursors (+E offset)
                         int* __restrict__ s_src, float* __restrict__ s_pp,
                         int* __restrict__ dpos, int N, int E)
{
    int e = blockIdx.x * 256 + threadIdx.x;
    if (e >= E) return;
    int sv = ei[e];
    int dv = ei[E + e];
    float p0 = pseudo[2 * (size_t)e];
    float p1 = pseudo[2 * (size_t)e + 1];
    int ps = atomicAdd(&start[sv], 1);
    int pd = atomicAdd(&start[N + dv], 1) - E;   // dst cursors carry +E from the joint scan
    s_src[ps] = sv;
    s_pp[2 * (size_t)ps]     = p0;
    s_pp[2 * (size_t)ps + 1] = p1;
    dpos[ps] = pd;
}

extern "C" void kernel_launch(void* const* d_in, const int* in_sizes, int n_in,
                              void* d_out, int out_size, void* d_ws, size_t ws_size,
                              hipStream_t stream) {
    const float* x      = (const float*)d_in[0];
    const int*   ei     = (const int*)  d_in[1];
    const float* pseudo = (const float*)d_in[2];
    const float* skip   = (const float*)d_in[3];
    const float* W1     = (const float*)d_in[4];
    const float* root1  = (const float*)d_in[5];
    const float* b1     = (const float*)d_in[6];
    const float* W2     = (const float*)d_in[7];
    const float* root2  = (const float*)d_in[8];
    const float* b2     = (const float*)d_in[9];

    const int N = in_sizes[0] / 64;
    const int E = in_sizes[1] / 2;
    float* out = (float*)d_out;

    // ws layout (67.6 MB for N=50000, E=400000):
    __hip_bfloat16* y    = (__hip_bfloat16*)d_ws;        // N*288 bf16
    __hip_bfloat16* msg  = y + (size_t)N * 288;          // E*32  bf16
    float* agg1  = (float*)(msg + (size_t)E * 32);       // N*32  f32
    int*   s_src = (int*)(agg1 + (size_t)N * 32);        // E
    int*   dpos  = s_src + E;                            // E
    float* s_pp  = (float*)(dpos + E);                   // 2E
    int*   start = (int*)(s_pp + 2 * (size_t)E);         // 2N
    int*   bsum  = start + 2 * N;                        // <=256

    const dim3 blk(256);
    const int tb   = (N + TN - 1) / TN;        // transform blocks
    const int eb   = (E + 7) / 8;              // msg blocks
    const int gb   = (N + 7) / 8;              // gather blocks
    const int e256 = (E + 255) / 256;
    const int n2k  = (2 * N + 1023) / 1024;    // joint scan blocks (<=256)
    int* rowend_d = start + N;                 // after scatter: dst CSR ends (+E)

    // ---- prep: dual counting sort, one joint 2N scan ----
    zero_kernel<<<n2k, 1024, 0, stream>>>(start, 2 * N);
    count_both_kernel<<<e256, blk, 0, stream>>>(ei, start, N, E);
    scan1_kernel<<<n2k, 1024, 0, stream>>>(start, bsum, 2 * N);
    scan2_kernel<<<1, 256, 0, stream>>>(bsum, n2k);
    scan3_kernel<<<n2k, 1024, 0, stream>>>(start, bsum, 2 * N);
    scatter_both_kernel<<<e256, blk, 0, stream>>>(ei, pseudo, start, s_src, s_pp, dpos, N, E);

    // ---- Layer 1 ----
    transform_kernel<64, 0><<<tb, blk, 0, stream>>>(x, nullptr, W1, root1, b1, y, agg1, N);
    msg_kernel<<<eb, blk, 0, stream>>>(s_src, s_pp, dpos, y, msg, E);
    gather_kernel<<<gb, blk, 0, stream>>>(rowend_d, msg, agg1, N, E);   // relu'd h1
    // ---- Layer 2: X = concat(h1, skip), W1; agg1 updated in place (tile-local) ----
    transform_kernel<64, 1><<<tb, blk, 0, stream>>>(agg1, skip, W1, root1, b1, y, agg1, N);
    msg_kernel<<<eb, blk, 0, stream>>>(s_src, s_pp, dpos, y, msg, E);
    gather_kernel<<<gb, blk, 0, stream>>>(rowend_d, msg, agg1, N, E);   // relu'd h2
    // ---- Layer 3: X = h2, W2; result into d_out ----
    transform_kernel<32, 0><<<tb, blk, 0, stream>>>(agg1, nullptr, W2, root2, b2, y, out, N);
    msg_kernel<<<eb, blk, 0, stream>>>(s_src, s_pp, dpos, y, msg, E);
    gather_kernel<<<gb, blk, 0, stream>>>(rowend_d, msg, out, N, E);    // relu fused
}

// Round 5
// 367.101 us; speedup vs baseline: 1.2006x; 1.1949x over previous
//
#include <hip/hip_runtime.h>

// 3-layer SplineConv (3x3, degree 2, open spline). Atomic-free per-layer path.
// Prep (once): dual counting sort (src & dst) via one 2N-wide scan.
//   Edge record packed into ONE float4 {src, dpos, p0, p1} stored at its
//   src-sorted slot (single 16-B scattered store per edge -> 1 dirty line,
//   was 3 in round 4: WRITE_SIZE 68 MB -> ~27 MB).
// Per layer:
//   transform: y[n,k*32+c] (bf16) = X @ W[k]; agg[n,c] = X @ root + bias (f32).
//   msg:       per src-sorted edge (16 lanes, 2ch/lane): m = sum q1a q0b y[src],
//              bf16x2 store into dst-sorted slot (no atomics).
//   gather:    per node (16 lanes, 2ch/lane): agg += contiguous msg rows; relu.

#define TN 32

__device__ __forceinline__ float bf2f(unsigned short u) {
    union { unsigned u; float f; } x; x.u = ((unsigned)u) << 16; return x.f;
}
__device__ __forceinline__ unsigned short f2bf(float f) {
    union { float f; unsigned u; } x; x.f = f;
    unsigned r = x.u + 0x7fffu + ((x.u >> 16) & 1u);   // round-to-nearest-even
    return (unsigned short)(r >> 16);
}

template<int CIN, int MODE>
__global__ __launch_bounds__(256)
void transform_kernel(const float* __restrict__ Xa, const float* __restrict__ Xb,
                      const float* __restrict__ W, const float* __restrict__ root,
                      const float* __restrict__ bias,
                      unsigned short* __restrict__ y, float* __restrict__ agg, int N)
{
    // MODE 0: X = Xa [N,CIN] (already relu'd where needed)
    // MODE 1: X[n,i] = i<32 ? Xa[n,i] : Xb[n,i-32]   (CIN=64)
    __shared__ float sX[TN][CIN + 1];
    const int t = threadIdx.x;
    const int base = blockIdx.x * TN;

    const int TOT = TN * CIN;
    for (int idx = t; idx < TOT; idx += 256) {
        int nl = idx / CIN;
        int i  = idx % CIN;
        int n  = base + nl;
        float v = 0.f;
        if (n < N) {
            if (MODE == 0) v = Xa[(size_t)n * CIN + i];
            else           v = (i < 32) ? Xa[(size_t)n * 32 + i]
                                        : Xb[(size_t)n * 32 + (i - 32)];
        }
        sX[nl][i] = v;
    }
    __syncthreads();

    const int c = t & 31;   // output channel
    const int q = t >> 5;   // 0..7, owns nodes q*4..q*4+3

    float acc[4][10];       // 40 accumulators/thread: no spill
    #pragma unroll
    for (int j = 0; j < 4; ++j)
        #pragma unroll
        for (int k = 0; k < 10; ++k) acc[j][k] = 0.f;

    for (int i = 0; i < CIN; ++i) {
        float wv[10];
        #pragma unroll
        for (int k = 0; k < 9; ++k)
            wv[k] = W[((size_t)k * CIN + i) * 32 + c];
        wv[9] = root[(size_t)i * 32 + c];
        #pragma unroll
        for (int j = 0; j < 4; ++j) {
            float xv = sX[q * 4 + j][i];
            #pragma unroll
            for (int k = 0; k < 10; ++k)
                acc[j][k] = fmaf(xv, wv[k], acc[j][k]);
        }
    }

    const float bv = bias[c];
    #pragma unroll
    for (int j = 0; j < 4; ++j) {
        int n = base + q * 4 + j;
        if (n < N) {
            #pragma unroll
            for (int k = 0; k < 9; ++k)
                y[(size_t)n * 288 + k * 32 + c] = f2bf(acc[j][k]);
            agg[(size_t)n * 32 + c] = acc[j][9] + bv;
        }
    }
}

// msg: 16 lanes per edge, 2 channels per lane (bf16x2)
__global__ __launch_bounds__(256)
void msg_kernel(const float4* __restrict__ erec,
                const unsigned short* __restrict__ y,
                unsigned short* __restrict__ msg, int E)
{
    const int t = threadIdx.x;
    const int e = blockIdx.x * 16 + (t >> 4);
    if (e >= E) return;
    const int l = t & 15;   // channel pair: channels 2l, 2l+1

    const float4 r = erec[e];
    const int src = __float_as_int(r.x);
    const int dp  = __float_as_int(r.y);
    const float p0 = r.z, p1 = r.w;

    const float qb0 = 0.5f * (1.f - p0) * (1.f - p0);
    const float qb1 = -p0 * p0 + p0 + 0.5f;
    const float qb2 = 0.5f * p0 * p0;
    const float qa0 = 0.5f * (1.f - p1) * (1.f - p1);
    const float qa1 = -p1 * p1 + p1 + 0.5f;
    const float qa2 = 0.5f * p1 * p1;
    const float qa[3] = {qa0, qa1, qa2};
    const float qb[3] = {qb0, qb1, qb2};

    const ushort2* yb = (const ushort2*)(y + (size_t)src * 288) + l;
    float sx = 0.f, sy = 0.f;
    #pragma unroll
    for (int a = 0; a < 3; ++a) {
        float mx = 0.f, my = 0.f;
        #pragma unroll
        for (int b = 0; b < 3; ++b) {
            ushort2 v = yb[(a * 3 + b) * 16];
            mx = fmaf(qb[b], bf2f(v.x), mx);
            my = fmaf(qb[b], bf2f(v.y), my);
        }
        sx = fmaf(qa[a], mx, sx);
        sy = fmaf(qa[a], my, sy);
    }
    ushort2 o; o.x = f2bf(sx); o.y = f2bf(sy);
    ((ushort2*)msg)[(size_t)dp * 16 + l] = o;
}

// gather: 16 lanes per node, 2 channels per lane; relu fused
__global__ __launch_bounds__(256)
void gather_kernel(const int* __restrict__ rowend_d,  // values carry +E offset
                   const unsigned short* __restrict__ msg,
                   float* __restrict__ agg, int N, int E)
{
    const int t = threadIdx.x;
    const int n = blockIdx.x * 16 + (t >> 4);
    if (n >= N) return;
    const int l = t & 15;

    const int e0 = ((n == 0) ? E : rowend_d[n - 1]) - E;
    const int e1 = rowend_d[n] - E;

    float2* ap = (float2*)agg + (size_t)n * 16 + l;
    float2 s = *ap;
    const ushort2* mp = (const ushort2*)msg + l;
    for (int e = e0; e < e1; ++e) {
        ushort2 v = mp[(size_t)e * 16];
        s.x += bf2f(v.x);
        s.y += bf2f(v.y);
    }
    s.x = fmaxf(s.x, 0.f);
    s.y = fmaxf(s.y, 0.f);
    *ap = s;
}

// ---------- prep: dual counting sort (src & dst), one 2N-wide scan ----------

__global__ __launch_bounds__(1024)
void zero_kernel(int* __restrict__ p, int n)
{
    int i = blockIdx.x * 1024 + threadIdx.x;
    if (i < n) p[i] = 0;
}

__global__ __launch_bounds__(256)
void count_both_kernel(const int* __restrict__ ei, int* __restrict__ hist, int N, int E)
{
    int e = blockIdx.x * 256 + threadIdx.x;
    if (e >= E) return;
    atomicAdd(&hist[ei[e]], 1);          // src bins [0,N)
    atomicAdd(&hist[N + ei[E + e]], 1);  // dst bins [N,2N)
}

__global__ __launch_bounds__(1024)
void scan1_kernel(int* __restrict__ hist, int* __restrict__ bsum, int n)
{
    __shared__ int s[1024];
    int tid = threadIdx.x;
    int i = blockIdx.x * 1024 + tid;
    int v = (i < n) ? hist[i] : 0;
    s[tid] = v;
    __syncthreads();
    for (int off = 1; off < 1024; off <<= 1) {
        int add = (tid >= off) ? s[tid - off] : 0;
        __syncthreads();
        s[tid] += add;
        __syncthreads();
    }
    if (i < n) hist[i] = s[tid] - v;          // exclusive within block
    if (tid == 1023) bsum[blockIdx.x] = s[1023];
}

__global__ __launch_bounds__(256)
void scan2_kernel(int* __restrict__ bsum, int nb)
{
    __shared__ int s[256];
    int tid = threadIdx.x;
    int v = (tid < nb) ? bsum[tid] : 0;
    s[tid] = v;
    __syncthreads();
    for (int off = 1; off < 256; off <<= 1) {
        int add = (tid >= off) ? s[tid - off] : 0;
        __syncthreads();
        s[tid] += add;
        __syncthreads();
    }
    if (tid < nb) bsum[tid] = s[tid] - v;     // exclusive
}

__global__ __launch_bounds__(1024)
void scan3_kernel(int* __restrict__ hist, const int* __restrict__ bsum, int n)
{
    int i = blockIdx.x * 1024 + threadIdx.x;
    if (i < n) hist[i] += bsum[blockIdx.x];
}

// one 16-B packed record per edge, scattered to its src-sorted slot
__global__ __launch_bounds__(256)
void scatter_both_kernel(const int* __restrict__ ei, const float* __restrict__ pseudo,
                         int* __restrict__ start,   // [0,N)=src cursors, [N,2N)=dst cursors(+E)
                         float4* __restrict__ erec, int N, int E)
{
    int e = blockIdx.x * 256 + threadIdx.x;
    if (e >= E) return;
    int sv = ei[e];
    int dv = ei[E + e];
    float p0 = pseudo[2 * (size_t)e];
    float p1 = pseudo[2 * (size_t)e + 1];
    int ps = atomicAdd(&start[sv], 1);
    int pd = atomicAdd(&start[N + dv], 1) - E;
    float4 r;
    r.x = __int_as_float(sv);
    r.y = __int_as_float(pd);
    r.z = p0;
    r.w = p1;
    erec[ps] = r;
}

extern "C" void kernel_launch(void* const* d_in, const int* in_sizes, int n_in,
                              void* d_out, int out_size, void* d_ws, size_t ws_size,
                              hipStream_t stream) {
    const float* x      = (const float*)d_in[0];
    const int*   ei     = (const int*)  d_in[1];
    const float* pseudo = (const float*)d_in[2];
    const float* skip   = (const float*)d_in[3];
    const float* W1     = (const float*)d_in[4];
    const float* root1  = (const float*)d_in[5];
    const float* b1     = (const float*)d_in[6];
    const float* W2     = (const float*)d_in[7];
    const float* root2  = (const float*)d_in[8];
    const float* b2     = (const float*)d_in[9];

    const int N = in_sizes[0] / 64;
    const int E = in_sizes[1] / 2;
    float* out = (float*)d_out;

    // ws layout (~67.6 MB): y[N*288 bf16] msg[E*32 bf16] agg1[N*32 f32]
    //                       erec[E float4] start[2N] bsum[256]
    unsigned short* y   = (unsigned short*)d_ws;
    unsigned short* msg = y + (size_t)N * 288;
    float*  agg1  = (float*)(msg + (size_t)E * 32);
    float4* erec  = (float4*)(agg1 + (size_t)N * 32);
    int*    start = (int*)(erec + E);
    int*    bsum  = start + 2 * N;

    const dim3 blk(256);
    const int tb   = (N + TN - 1) / TN;
    const int eb   = (E + 15) / 16;
    const int gb   = (N + 15) / 16;
    const int e256 = (E + 255) / 256;
    const int n2k  = (2 * N + 1023) / 1024;
    int* rowend_d = start + N;   // after scatter: dst CSR ends (+E offset)

    // ---- prep ----
    zero_kernel<<<n2k, 1024, 0, stream>>>(start, 2 * N);
    count_both_kernel<<<e256, blk, 0, stream>>>(ei, start, N, E);
    scan1_kernel<<<n2k, 1024, 0, stream>>>(start, bsum, 2 * N);
    scan2_kernel<<<1, 256, 0, stream>>>(bsum, n2k);
    scan3_kernel<<<n2k, 1024, 0, stream>>>(start, bsum, 2 * N);
    scatter_both_kernel<<<e256, blk, 0, stream>>>(ei, pseudo, start, erec, N, E);

    // ---- Layer 1 ----
    transform_kernel<64, 0><<<tb, blk, 0, stream>>>(x, nullptr, W1, root1, b1, y, agg1, N);
    msg_kernel<<<eb, blk, 0, stream>>>(erec, y, msg, E);
    gather_kernel<<<gb, blk, 0, stream>>>(rowend_d, msg, agg1, N, E);   // h1 (relu'd)
    // ---- Layer 2: X = concat(h1, skip), W1 ----
    transform_kernel<64, 1><<<tb, blk, 0, stream>>>(agg1, skip, W1, root1, b1, y, agg1, N);
    msg_kernel<<<eb, blk, 0, stream>>>(erec, y, msg, E);
    gather_kernel<<<gb, blk, 0, stream>>>(rowend_d, msg, agg1, N, E);   // h2 (relu'd)
    // ---- Layer 3: X = h2, W2 -> d_out ----
    transform_kernel<32, 0><<<tb, blk, 0, stream>>>(agg1, nullptr, W2, root2, b2, y, out, N);
    msg_kernel<<<eb, blk, 0, stream>>>(erec, y, msg, E);
    gather_kernel<<<gb, blk, 0, stream>>>(rowend_d, msg, out, N, E);    // relu fused
}

// Round 6
// 325.851 us; speedup vs baseline: 1.3526x; 1.1266x over previous
//
#include <hip/hip_runtime.h>

// 3-layer SplineConv (3x3, degree 2, open spline). Atomic-free pipeline.
// Round 6: transform is now an MFMA GEMM (bf16 in / fp32 acc):
//   C[64 nodes][320] = X[64][CIN] @ Wcat[CIN][320],  Wcat = [W0..W8 | root]
//   cols 0..287 -> y (bf16), cols 288..319 -> agg = root-term + bias (f32).
//   B is staged once in prep as Wt[320][CIN] bf16 (N-major, K-contig) so both
//   A and B fragments are 16-B contiguous loads (m97 gemm_bt structure).
// msg/gather/prep (dual counting sort, packed float4 edge records) unchanged.

typedef __attribute__((ext_vector_type(8))) short short8;
typedef __attribute__((ext_vector_type(4))) float f32x4;

__device__ __forceinline__ float bf2f(unsigned short u) {
    union { unsigned u; float f; } x; x.u = ((unsigned)u) << 16; return x.f;
}
__device__ __forceinline__ unsigned short f2bf(float f) {
    union { float f; unsigned u; } x; x.f = f;
    unsigned r = x.u + 0x7fffu + ((x.u >> 16) & 1u);   // RNE
    return (unsigned short)(r >> 16);
}
__device__ __forceinline__ short8 cvt8(const float* p) {
    float4 a = *(const float4*)p;
    float4 b = *(const float4*)(p + 4);
    short8 r;
    r[0] = (short)f2bf(a.x); r[1] = (short)f2bf(a.y);
    r[2] = (short)f2bf(a.z); r[3] = (short)f2bf(a.w);
    r[4] = (short)f2bf(b.x); r[5] = (short)f2bf(b.y);
    r[6] = (short)f2bf(b.z); r[7] = (short)f2bf(b.w);
    return r;
}

// MODE 0: X = Xa [N,64]            (layer 1: x)
// MODE 1: X = [Xa[N,32] | Xb[N,32]] (layer 2: concat(h1, skip))
// MODE 2: X = Xa [N,32]            (layer 3: h2)
template<int MODE>
__global__ __launch_bounds__(256)
void transform_mfma(const float* __restrict__ Xa, const float* __restrict__ Xb,
                    const unsigned short* __restrict__ Wt,  // [320][CIN] bf16
                    const float* __restrict__ bias,
                    unsigned short* __restrict__ y, float* __restrict__ agg, int N)
{
    const int CIN = (MODE == 0) ? 64 : ((MODE == 1) ? 64 : 32);
    const int t    = threadIdx.x;
    const int wv   = t >> 6;       // wave 0..3
    const int lane = t & 63;
    const int lc   = lane & 15;    // tile row (A) / tile col (C)
    const int q    = lane >> 4;    // quad
    const int base = blockIdx.x * 64 + wv * 16;

    // ---- A fragments: 8 fp32 -> bf16 per frag; k = q*8 + j (+32 for a1) ----
    int na = base + lc;
    if (na >= N) na = N - 1;       // clamp (input buffers are exactly N rows)
    short8 a0, a1;
    if (MODE == 0) {
        const float* p = Xa + (size_t)na * 64 + q * 8;
        a0 = cvt8(p);
        a1 = cvt8(p + 32);
    } else if (MODE == 1) {
        a0 = cvt8(Xa + (size_t)na * 32 + q * 8);
        a1 = cvt8(Xb + (size_t)na * 32 + q * 8);
    } else {
        a0 = cvt8(Xa + (size_t)na * 32 + q * 8);
    }

    // ---- 20 col-tiles of 16; K-loop unrolled (K = CIN) ----
    f32x4 acc[20];
    #pragma unroll
    for (int nt = 0; nt < 20; ++nt) acc[nt] = (f32x4){0.f, 0.f, 0.f, 0.f};

    #pragma unroll
    for (int nt = 0; nt < 20; ++nt) {
        const unsigned short* wp = Wt + ((size_t)(nt * 16 + lc)) * CIN + q * 8;
        short8 b0 = *(const short8*)wp;
        acc[nt] = __builtin_amdgcn_mfma_f32_16x16x32_bf16(a0, b0, acc[nt], 0, 0, 0);
        if (MODE != 2) {
            short8 b1 = *(const short8*)(wp + 32);
            acc[nt] = __builtin_amdgcn_mfma_f32_16x16x32_bf16(a1, b1, acc[nt], 0, 0, 0);
        }
    }

    // ---- epilogue: C row = q*4 + r (node), col = lc ----
    #pragma unroll
    for (int nt = 0; nt < 20; ++nt) {
        #pragma unroll
        for (int r = 0; r < 4; ++r) {
            int n = base + q * 4 + r;
            if (n >= N) continue;
            if (nt < 18) {
                y[(size_t)n * 288 + nt * 16 + lc] = f2bf(acc[nt][r]);
            } else {
                int c = (nt - 18) * 16 + lc;
                agg[(size_t)n * 32 + c] = acc[nt][r] + bias[c];
            }
        }
    }
}

// build Wt[320][CIN] bf16 from W[9,CIN,32] f32 and root[CIN,32] f32
template<int CIN>
__global__ __launch_bounds__(256)
void build_wt_kernel(const float* __restrict__ W, const float* __restrict__ root,
                     unsigned short* __restrict__ Wt)
{
    int idx = blockIdx.x * 256 + threadIdx.x;
    if (idx >= 320 * CIN) return;
    int col = idx / CIN;
    int k   = idx % CIN;
    float v = (col < 288) ? W[((size_t)(col >> 5) * CIN + k) * 32 + (col & 31)]
                          : root[(size_t)k * 32 + (col - 288)];
    Wt[idx] = f2bf(v);
}

// msg: 16 lanes per edge, 2 channels per lane (bf16x2); no atomics
__global__ __launch_bounds__(256)
void msg_kernel(const float4* __restrict__ erec,
                const unsigned short* __restrict__ y,
                unsigned short* __restrict__ msg, int E)
{
    const int t = threadIdx.x;
    const int e = blockIdx.x * 16 + (t >> 4);
    if (e >= E) return;
    const int l = t & 15;

    const float4 r = erec[e];
    const int src = __float_as_int(r.x);
    const int dp  = __float_as_int(r.y);
    const float p0 = r.z, p1 = r.w;

    const float qb[3] = {0.5f * (1.f - p0) * (1.f - p0), -p0 * p0 + p0 + 0.5f, 0.5f * p0 * p0};
    const float qa[3] = {0.5f * (1.f - p1) * (1.f - p1), -p1 * p1 + p1 + 0.5f, 0.5f * p1 * p1};

    const ushort2* yb = (const ushort2*)(y + (size_t)src * 288) + l;
    float sx = 0.f, sy = 0.f;
    #pragma unroll
    for (int a = 0; a < 3; ++a) {
        float mx = 0.f, my = 0.f;
        #pragma unroll
        for (int b = 0; b < 3; ++b) {
            ushort2 v = yb[(a * 3 + b) * 16];
            mx = fmaf(qb[b], bf2f(v.x), mx);
            my = fmaf(qb[b], bf2f(v.y), my);
        }
        sx = fmaf(qa[a], mx, sx);
        sy = fmaf(qa[a], my, sy);
    }
    ushort2 o; o.x = f2bf(sx); o.y = f2bf(sy);
    ((ushort2*)msg)[(size_t)dp * 16 + l] = o;
}

// gather: 16 lanes per node, 2 channels per lane; relu fused; in-place on agg
__global__ __launch_bounds__(256)
void gather_kernel(const int* __restrict__ rowend_d,  // values carry +E offset
                   const unsigned short* __restrict__ msg,
                   float* __restrict__ agg, int N, int E)
{
    const int t = threadIdx.x;
    const int n = blockIdx.x * 16 + (t >> 4);
    if (n >= N) return;
    const int l = t & 15;

    const int e0 = ((n == 0) ? E : rowend_d[n - 1]) - E;
    const int e1 = rowend_d[n] - E;

    float2* ap = (float2*)agg + (size_t)n * 16 + l;
    float2 s = *ap;
    const ushort2* mp = (const ushort2*)msg + l;
    for (int e = e0; e < e1; ++e) {
        ushort2 v = mp[(size_t)e * 16];
        s.x += bf2f(v.x);
        s.y += bf2f(v.y);
    }
    s.x = fmaxf(s.x, 0.f);
    s.y = fmaxf(s.y, 0.f);
    *ap = s;
}

// ---------- prep: dual counting sort (src & dst), one 2N-wide scan ----------

__global__ __launch_bounds__(1024)
void zero_kernel(int* __restrict__ p, int n)
{
    int i = blockIdx.x * 1024 + threadIdx.x;
    if (i < n) p[i] = 0;
}

__global__ __launch_bounds__(256)
void count_both_kernel(const int* __restrict__ ei, int* __restrict__ hist, int N, int E)
{
    int e = blockIdx.x * 256 + threadIdx.x;
    if (e >= E) return;
    atomicAdd(&hist[ei[e]], 1);
    atomicAdd(&hist[N + ei[E + e]], 1);
}

__global__ __launch_bounds__(1024)
void scan1_kernel(int* __restrict__ hist, int* __restrict__ bsum, int n)
{
    __shared__ int s[1024];
    int tid = threadIdx.x;
    int i = blockIdx.x * 1024 + tid;
    int v = (i < n) ? hist[i] : 0;
    s[tid] = v;
    __syncthreads();
    for (int off = 1; off < 1024; off <<= 1) {
        int add = (tid >= off) ? s[tid - off] : 0;
        __syncthreads();
        s[tid] += add;
        __syncthreads();
    }
    if (i < n) hist[i] = s[tid] - v;
    if (tid == 1023) bsum[blockIdx.x] = s[1023];
}

__global__ __launch_bounds__(256)
void scan2_kernel(int* __restrict__ bsum, int nb)
{
    __shared__ int s[256];
    int tid = threadIdx.x;
    int v = (tid < nb) ? bsum[tid] : 0;
    s[tid] = v;
    __syncthreads();
    for (int off = 1; off < 256; off <<= 1) {
        int add = (tid >= off) ? s[tid - off] : 0;
        __syncthreads();
        s[tid] += add;
        __syncthreads();
    }
    if (tid < nb) bsum[tid] = s[tid] - v;
}

__global__ __launch_bounds__(1024)
void scan3_kernel(int* __restrict__ hist, const int* __restrict__ bsum, int n)
{
    int i = blockIdx.x * 1024 + threadIdx.x;
    if (i < n) hist[i] += bsum[blockIdx.x];
}

__global__ __launch_bounds__(256)
void scatter_both_kernel(const int* __restrict__ ei, const float* __restrict__ pseudo,
                         int* __restrict__ start,
                         float4* __restrict__ erec, int N, int E)
{
    int e = blockIdx.x * 256 + threadIdx.x;
    if (e >= E) return;
    int sv = ei[e];
    int dv = ei[E + e];
    float p0 = pseudo[2 * (size_t)e];
    float p1 = pseudo[2 * (size_t)e + 1];
    int ps = atomicAdd(&start[sv], 1);
    int pd = atomicAdd(&start[N + dv], 1) - E;
    float4 r;
    r.x = __int_as_float(sv);
    r.y = __int_as_float(pd);
    r.z = p0;
    r.w = p1;
    erec[ps] = r;
}

extern "C" void kernel_launch(void* const* d_in, const int* in_sizes, int n_in,
                              void* d_out, int out_size, void* d_ws, size_t ws_size,
                              hipStream_t stream) {
    const float* x      = (const float*)d_in[0];
    const int*   ei     = (const int*)  d_in[1];
    const float* pseudo = (const float*)d_in[2];
    const float* skip   = (const float*)d_in[3];
    const float* W1     = (const float*)d_in[4];
    const float* root1  = (const float*)d_in[5];
    const float* b1     = (const float*)d_in[6];
    const float* W2     = (const float*)d_in[7];
    const float* root2  = (const float*)d_in[8];
    const float* b2     = (const float*)d_in[9];

    const int N = in_sizes[0] / 64;
    const int E = in_sizes[1] / 2;
    float* out = (float*)d_out;

    // ws (~67.7 MB): y[N*288 bf16] msg[E*32 bf16] agg1[N*32 f32] erec[E f4]
    //                start[2N] bsum[256] Wt1[320*64 bf16] Wt2[320*32 bf16]
    unsigned short* y   = (unsigned short*)d_ws;
    unsigned short* msg = y + (size_t)N * 288;
    float*  agg1  = (float*)(msg + (size_t)E * 32);
    float4* erec  = (float4*)(agg1 + (size_t)N * 32);
    int*    start = (int*)(erec + E);
    int*    bsum  = start + 2 * N;
    unsigned short* Wt1 = (unsigned short*)(bsum + 256);
    unsigned short* Wt2 = Wt1 + 320 * 64;

    const dim3 blk(256);
    const int tb   = (N + 63) / 64;
    const int eb   = (E + 15) / 16;
    const int gb   = (N + 15) / 16;
    const int e256 = (E + 255) / 256;
    const int n2k  = (2 * N + 1023) / 1024;
    int* rowend_d = start + N;

    // ---- prep ----
    zero_kernel<<<n2k, 1024, 0, stream>>>(start, 2 * N);
    count_both_kernel<<<e256, blk, 0, stream>>>(ei, start, N, E);
    build_wt_kernel<64><<<(320 * 64 + 255) / 256, blk, 0, stream>>>(W1, root1, Wt1);
    build_wt_kernel<32><<<(320 * 32 + 255) / 256, blk, 0, stream>>>(W2, root2, Wt2);
    scan1_kernel<<<n2k, 1024, 0, stream>>>(start, bsum, 2 * N);
    scan2_kernel<<<1, 256, 0, stream>>>(bsum, n2k);
    scan3_kernel<<<n2k, 1024, 0, stream>>>(start, bsum, 2 * N);
    scatter_both_kernel<<<e256, blk, 0, stream>>>(ei, pseudo, start, erec, N, E);

    // ---- Layer 1 ----
    transform_mfma<0><<<tb, blk, 0, stream>>>(x, nullptr, Wt1, b1, y, agg1, N);
    msg_kernel<<<eb, blk, 0, stream>>>(erec, y, msg, E);
    gather_kernel<<<gb, blk, 0, stream>>>(rowend_d, msg, agg1, N, E);   // h1 (relu'd)
    // ---- Layer 2: X = concat(h1, skip) ----
    transform_mfma<1><<<tb, blk, 0, stream>>>(agg1, skip, Wt1, b1, y, agg1, N);
    msg_kernel<<<eb, blk, 0, stream>>>(erec, y, msg, E);
    gather_kernel<<<gb, blk, 0, stream>>>(rowend_d, msg, agg1, N, E);   // h2 (relu'd)
    // ---- Layer 3 -> d_out ----
    transform_mfma<2><<<tb, blk, 0, stream>>>(agg1, nullptr, Wt2, b2, y, out, N);
    msg_kernel<<<eb, blk, 0, stream>>>(erec, y, msg, E);
    gather_kernel<<<gb, blk, 0, stream>>>(rowend_d, msg, out, N, E);    // relu fused
}